// Round 2
// baseline (140.082 us; speedup 1.0000x reference)
//
#include <hip/hip_runtime.h>

typedef __attribute__((ext_vector_type(8))) short short8;
typedef __attribute__((ext_vector_type(4))) float f32x4;
typedef __attribute__((ext_vector_type(4))) unsigned short u16x4;
typedef unsigned short u16;
typedef unsigned int u32;

#define MFMA16 __builtin_amdgcn_mfma_f32_16x16x32_bf16

__device__ __forceinline__ u16 f2bf(float f) {
    u32 u = __builtin_bit_cast(u32, f);
    return (u16)((u + 0x7FFFu + ((u >> 16) & 1u)) >> 16);
}

// truncation split: f ~= hi + lo with ~16-bit combined mantissa (exact enough: 2^-16 rel)
__device__ __forceinline__ void split2(float f, u16& hi, u16& lo) {
    u32 u = __builtin_bit_cast(u32, f);
    hi = (u16)(u >> 16);
    float hf = __builtin_bit_cast(float, u & 0xFFFF0000u);
    float r = f - hf;             // exact (Sterbenz)
    lo = (u16)(__builtin_bit_cast(u32, r) >> 16);
}

// swizzle for [rows][32 bf16 = 64B] tiles, 4x16B slots/row: 2-way (free) on frag reads
__device__ __forceinline__ int swzA(int row, int slot) {
    return row * 64 + ((slot ^ ((row >> 1) & 3)) << 4);
}

// ---------------- weight transpose: w[K][N] -> wt[N][K] ----------------
__global__ void __launch_bounds__(256) k_tr(const float* __restrict__ w, float* __restrict__ wt,
                                            int K, int N) {
    int idx = blockIdx.x * 256 + threadIdx.x;
    if (idx >= K * N) return;
    int k = idx / N, n = idx - k * N;
    wt[n * K + k] = w[idx];
}

// ---------------- split-bf16 MFMA GEMM: C[M,N] = act(A[M,K] @ Bt[N,K]^T + bias) ----------------
template <int K, int BN, bool RELU>
__global__ void __launch_bounds__(256, 2) k_gemm(const float* __restrict__ A,
                                                 const float* __restrict__ Bt,
                                                 const float* __restrict__ bias,
                                                 float* __restrict__ C, const int N) {
    constexpr int NT = BN / 16;
    __shared__ __align__(16) char smem[16384];
    char* const Ah = smem;
    char* const Al = smem + 4096;
    char* const Bh = smem + 8192;
    char* const Bl = smem + 12288;
    const int tid = threadIdx.x, lane = tid & 63, w = tid >> 6;
    const int frow = lane & 15, fg = lane >> 4;
    const int m0 = blockIdx.x * 64, n0 = blockIdx.y * BN;
    const int srow = tid >> 2, sc = tid & 3;
    const int swa = swzA(srow, sc);
    const bool doB = (BN == 64) || (tid < 128);
    const float* gA = A + (m0 + srow) * K + sc * 8;
    const float* gB = Bt + (n0 + srow) * K + sc * 8;

    f32x4 acc[NT];
    float bv[NT];
#pragma unroll
    for (int nt = 0; nt < NT; nt++) {
        acc[nt] = {0.f, 0.f, 0.f, 0.f};
        bv[nt] = bias[n0 + nt * 16 + frow];
    }
    const int fra = swzA(w * 16 + frow, fg);
    int frb[NT];
#pragma unroll
    for (int nt = 0; nt < NT; nt++) frb[nt] = swzA(nt * 16 + frow, fg);

    for (int k0 = 0; k0 < K; k0 += 32) {
        f32x4 a0 = *(const f32x4*)(gA + k0);
        f32x4 a1 = *(const f32x4*)(gA + k0 + 4);
        f32x4 b0 = {0.f, 0.f, 0.f, 0.f}, b1 = {0.f, 0.f, 0.f, 0.f};
        if (doB) {
            b0 = *(const f32x4*)(gB + k0);
            b1 = *(const f32x4*)(gB + k0 + 4);
        }
        __syncthreads();  // previous iteration's frag reads done before overwrite
        {
            short8 ah8, al8;
#pragma unroll
            for (int i = 0; i < 4; i++) { u16 hh, ll; split2(a0[i], hh, ll); ah8[i] = (short)hh; al8[i] = (short)ll; }
#pragma unroll
            for (int i = 0; i < 4; i++) { u16 hh, ll; split2(a1[i], hh, ll); ah8[4 + i] = (short)hh; al8[4 + i] = (short)ll; }
            *(short8*)(Ah + swa) = ah8;
            *(short8*)(Al + swa) = al8;
        }
        if (doB) {
            short8 bh8, bl8;
#pragma unroll
            for (int i = 0; i < 4; i++) { u16 hh, ll; split2(b0[i], hh, ll); bh8[i] = (short)hh; bl8[i] = (short)ll; }
#pragma unroll
            for (int i = 0; i < 4; i++) { u16 hh, ll; split2(b1[i], hh, ll); bh8[4 + i] = (short)hh; bl8[4 + i] = (short)ll; }
            *(short8*)(Bh + swa) = bh8;
            *(short8*)(Bl + swa) = bl8;
        }
        __syncthreads();
        const short8 afh = *(const short8*)(Ah + fra);
        const short8 afl = *(const short8*)(Al + fra);
#pragma unroll
        for (int nt = 0; nt < NT; nt++) {
            const short8 bfh = *(const short8*)(Bh + frb[nt]);
            const short8 bfl = *(const short8*)(Bl + frb[nt]);
            acc[nt] = MFMA16(afh, bfh, acc[nt], 0, 0, 0);
            acc[nt] = MFMA16(afh, bfl, acc[nt], 0, 0, 0);
            acc[nt] = MFMA16(afl, bfh, acc[nt], 0, 0, 0);
        }
    }
#pragma unroll
    for (int nt = 0; nt < NT; nt++) {
#pragma unroll
        for (int r = 0; r < 4; r++) {
            float v = acc[nt][r] + bv[nt];
            if (RELU) v = fmaxf(v, 0.f);
            C[(m0 + w * 16 + fg * 4 + r) * N + (n0 + nt * 16 + frow)] = v;
        }
    }
}

// ---------------- post: sq, h hi/lo, B1t = (h@gw1)^T / N ----------------
__global__ void __launch_bounds__(256) k_post(const float* __restrict__ H,
                                              const float* __restrict__ gw1,
                                              u16* __restrict__ hhi, u16* __restrict__ hlo,
                                              float* __restrict__ sqv, u16* __restrict__ B1t) {
    __shared__ float gs[512];
    const int tid = threadIdx.x;
    gs[tid] = gw1[tid];
    gs[tid + 256] = gw1[tid + 256];
    __syncthreads();
    const int j = blockIdx.x * 256 + tid;
    float h[32];
#pragma unroll
    for (int q = 0; q < 8; q++) {
        f32x4 v = *(const f32x4*)(H + j * 32 + q * 4);
        h[q * 4 + 0] = v[0]; h[q * 4 + 1] = v[1]; h[q * 4 + 2] = v[2]; h[q * 4 + 3] = v[3];
    }
    float s = 0.f;
#pragma unroll
    for (int k = 0; k < 32; k++) s = fmaf(h[k], h[k], s);
    sqv[j] = s;
#pragma unroll
    for (int q = 0; q < 4; q++) {
        short8 vh, vl;
#pragma unroll
        for (int e = 0; e < 8; e++) {
            u16 hh, ll;
            split2(h[q * 8 + e], hh, ll);
            vh[e] = (short)hh; vl[e] = (short)ll;
        }
        *(short8*)(hhi + j * 32 + q * 8) = vh;
        *(short8*)(hlo + j * 32 + q * 8) = vl;
    }
    const float inv = 0.0001220703125f;  // 1/8192
#pragma unroll
    for (int f = 0; f < 16; f++) {
        float a = 0.f;
#pragma unroll
        for (int k = 0; k < 32; k++) a = fmaf(h[k], gs[k * 16 + f], a);
        B1t[f * 8192 + j] = f2bf(a * inv);
    }
}

// ---------------- fused aggregation: P[chunk][i][f] = sum_j sigmoid(t*(d(i,j)+th)) * Bt[f][j] ----------------
__global__ void __launch_bounds__(256, 2) k_agg(const u16* __restrict__ hhi,
                                                const u16* __restrict__ hlo,
                                                const float* __restrict__ sqv,
                                                const u16* __restrict__ Bt,
                                                float* __restrict__ P,
                                                const float* __restrict__ tp,
                                                const float* __restrict__ thp) {
    __shared__ __align__(16) char smem[25088];
    const int tid = threadIdx.x;
    const int lane = tid & 63;
    const int w = tid >> 6;
    const int frow = lane & 15, fg = lane >> 4;
    const int dstbase = blockIdx.x * 64;
    const int chunk = blockIdx.y;
    const float t = tp[0], th = thp[0];
    const float c1 = -t * 1.44269504088896340736f;  // -t*log2(e)
    const float c0 = c1 * th;

    char* const hdh_p = smem;
    char* const hdl_p = smem + 4096;
    char* const hsh_p = smem + 8192;
    char* const hsl_p = smem + 12288;
    float* const sqd = (float*)(smem + 16384);
    float* const sqs = (float*)(smem + 16640);
    char* const astr = smem + 16896 + w * 2048;  // per-wave private a-strip [16][64] bf16

    const int srow = tid >> 2, sc = tid & 3;
    const int swa = swzA(srow, sc);

    {  // stage dst tile hi/lo + sq_dst
        short8 vh = *(const short8*)(hhi + (dstbase + srow) * 32 + sc * 8);
        short8 vl = *(const short8*)(hlo + (dstbase + srow) * 32 + sc * 8);
        *(short8*)(hdh_p + swa) = vh;
        *(short8*)(hdl_p + swa) = vl;
        if (tid < 64) sqd[tid] = sqv[dstbase + tid];
    }
    __syncthreads();

    const int fra = swzA(w * 16 + frow, fg);
    const short8 hdh = *(const short8*)(hdh_p + fra);
    const short8 hdl = *(const short8*)(hdl_p + fra);
    const float sq_i = sqd[w * 16 + frow];
    const int il = w * 16 + frow;

    int hsfa[4], aw_off[4], ard[2];
#pragma unroll
    for (int jj = 0; jj < 4; jj++) hsfa[jj] = swzA(jj * 16 + frow, fg);
#pragma unroll
    for (int jj = 0; jj < 4; jj++)
        aw_off[jj] = frow * 128 + (((2 * jj + (fg >> 1)) ^ (frow & 7)) << 4) + ((fg & 1) << 3);
#pragma unroll
    for (int ks = 0; ks < 2; ks++) ard[ks] = frow * 128 + (((4 * ks + fg) ^ (frow & 7)) << 4);

    f32x4 outacc = {0.f, 0.f, 0.f, 0.f};
    const u16* bgp = Bt + frow * 8192;

    for (int jt = chunk * 16; jt < chunk * 16 + 16; ++jt) {
        const int jbase = jt * 64;
        // B fragments straight from global (L2-resident, contiguous 16B per lane)
        const short8 bf0 = *(const short8*)(bgp + jbase + fg * 8);
        const short8 bf1 = *(const short8*)(bgp + jbase + 32 + fg * 8);
        // src tile loads (issue before barrier)
        const short8 vh = *(const short8*)(hhi + (jbase + srow) * 32 + sc * 8);
        const short8 vl = *(const short8*)(hlo + (jbase + srow) * 32 + sc * 8);
        const int il_cmp = (jbase == dstbase) ? il : -1;
        __syncthreads();  // prev iteration's LDS reads complete
        *(short8*)(hsh_p + swa) = vh;
        *(short8*)(hsl_p + swa) = vl;
        if (tid < 64) sqs[tid] = sqv[jbase + tid];
        __syncthreads();

        short8 hsh[4], hsl[4];
#pragma unroll
        for (int jj = 0; jj < 4; jj++) {
            hsh[jj] = *(const short8*)(hsh_p + hsfa[jj]);
            hsl[jj] = *(const short8*)(hsl_p + hsfa[jj]);
        }
        // S' = Hs . Hd^T (swapped so acc->PV-A-frag transpose is a packed b64 LDS write)
        f32x4 sacc[4];
#pragma unroll
        for (int jj = 0; jj < 4; jj++) {
            f32x4 z = {0.f, 0.f, 0.f, 0.f};
            z = MFMA16(hsh[jj], hdh, z, 0, 0, 0);
            z = MFMA16(hsh[jj], hdl, z, 0, 0, 0);
            z = MFMA16(hsl[jj], hdh, z, 0, 0, 0);
            sacc[jj] = z;
        }
        // elementwise: d2 -> d -> a = sigmoid(t*(d+th)) -> bf16 -> a-strip
#pragma unroll
        for (int jj = 0; jj < 4; jj++) {
            u16x4 av;
#pragma unroll
            for (int r = 0; r < 4; r++) {
                const int jl = jj * 16 + fg * 4 + r;
                const float sqj = sqs[jl];
                float d2 = fmaf(sacc[jj][r], -2.f, sq_i + sqj);
                d2 = fmaxf(d2, 0.f);
                float d = __builtin_amdgcn_sqrtf(d2);
                if (jl == il_cmp) d = 0.f;  // exact diagonal (ref: where(d2>0,...))
                const float zz = fmaf(d, c1, c0);
                const float aa = __builtin_amdgcn_rcpf(1.f + __builtin_amdgcn_exp2f(zz));
                av[r] = f2bf(aa);
            }
            *(u16x4*)(astr + aw_off[jj]) = av;
        }
        // PV: out += a(16x64) @ B(64x16)
        const short8 af0 = *(const short8*)(astr + ard[0]);
        const short8 af1 = *(const short8*)(astr + ard[1]);
        outacc = MFMA16(af0, bf0, outacc, 0, 0, 0);
        outacc = MFMA16(af1, bf1, outacc, 0, 0, 0);
    }
#pragma unroll
    for (int r = 0; r < 4; r++) {
        const int ig = dstbase + w * 16 + fg * 4 + r;
        P[(chunk * 8192 + ig) * 16 + frow] = outacc[r];
    }
}

// ---------------- reduce partials -> g1 -> B2t = (g1@gw2)^T / N (rows 8..15 zero) ----------------
__global__ void __launch_bounds__(256) k_reduce1(const float* __restrict__ P,
                                                 const float* __restrict__ gw2,
                                                 const float* __restrict__ gb1,
                                                 u16* __restrict__ B2t) {
    __shared__ float gs[128];
    const int tid = threadIdx.x;
    if (tid < 128) gs[tid] = gw2[tid];
    __syncthreads();
    const int j = blockIdx.x * 256 + tid;
    float g[16];
#pragma unroll
    for (int q = 0; q < 4; q++) {
        f32x4 v = *(const f32x4*)(P + j * 16 + q * 4);
        g[q * 4 + 0] = v[0]; g[q * 4 + 1] = v[1]; g[q * 4 + 2] = v[2]; g[q * 4 + 3] = v[3];
    }
#pragma unroll
    for (int c = 1; c < 8; c++) {
#pragma unroll
        for (int q = 0; q < 4; q++) {
            f32x4 v = *(const f32x4*)(P + (c * 8192 + j) * 16 + q * 4);
            g[q * 4 + 0] += v[0]; g[q * 4 + 1] += v[1]; g[q * 4 + 2] += v[2]; g[q * 4 + 3] += v[3];
        }
    }
#pragma unroll
    for (int f = 0; f < 16; f++) g[f] = fmaxf(g[f] + gb1[f], 0.f);
    const float inv = 0.0001220703125f;
#pragma unroll
    for (int f2 = 0; f2 < 8; f2++) {
        float a = 0.f;
#pragma unroll
        for (int k = 0; k < 16; k++) a = fmaf(g[k], gs[k * 8 + f2], a);
        B2t[f2 * 8192 + j] = f2bf(a * inv);
    }
#pragma unroll
    for (int f2 = 8; f2 < 16; f2++) B2t[f2 * 8192 + j] = 0;
}

// ---------------- final: g2 -> relu(g2@lw1+lb1) -> @lw2+lb2 ----------------
__global__ void __launch_bounds__(256) k_final(const float* __restrict__ P,
                                               const float* __restrict__ gb2,
                                               const float* __restrict__ lw1,
                                               const float* __restrict__ lb1,
                                               const float* __restrict__ lw2,
                                               const float* __restrict__ lb2,
                                               float* __restrict__ out) {
    __shared__ float s1[128], s2[256];
    const int tid = threadIdx.x;
    if (tid < 128) s1[tid] = lw1[tid];
    s2[tid] = lw2[tid];
    __syncthreads();
    const int j = blockIdx.x * 256 + tid;
    float g[8];
#pragma unroll
    for (int q = 0; q < 2; q++) {
        f32x4 v = *(const f32x4*)(P + j * 16 + q * 4);
        g[q * 4 + 0] = v[0]; g[q * 4 + 1] = v[1]; g[q * 4 + 2] = v[2]; g[q * 4 + 3] = v[3];
    }
#pragma unroll
    for (int c = 1; c < 8; c++) {
#pragma unroll
        for (int q = 0; q < 2; q++) {
            f32x4 v = *(const f32x4*)(P + (c * 8192 + j) * 16 + q * 4);
            g[q * 4 + 0] += v[0]; g[q * 4 + 1] += v[1]; g[q * 4 + 2] += v[2]; g[q * 4 + 3] += v[3];
        }
    }
#pragma unroll
    for (int f = 0; f < 8; f++) g[f] = fmaxf(g[f] + gb2[f], 0.f);
    float l1[16];
#pragma unroll
    for (int f = 0; f < 16; f++) {
        float a = lb1[f];
#pragma unroll
        for (int k = 0; k < 8; k++) a = fmaf(g[k], s1[k * 16 + f], a);
        l1[f] = fmaxf(a, 0.f);
    }
#pragma unroll
    for (int q = 0; q < 4; q++) {
        f32x4 v;
#pragma unroll
        for (int e = 0; e < 4; e++) {
            const int f = q * 4 + e;
            float a = lb2[f];
#pragma unroll
            for (int k = 0; k < 16; k++) a = fmaf(l1[k], s2[k * 16 + f], a);
            v[e] = a;
        }
        *(f32x4*)(out + j * 16 + q * 4) = v;
    }
}

extern "C" void kernel_launch(void* const* d_in, const int* in_sizes, int n_in,
                              void* d_out, int out_size, void* d_ws, size_t ws_size,
                              hipStream_t stream) {
    (void)in_sizes; (void)n_in; (void)out_size; (void)ws_size;
    const float* x   = (const float*)d_in[0];
    const float* w1  = (const float*)d_in[1];
    const float* b1  = (const float*)d_in[2];
    const float* w2  = (const float*)d_in[3];
    const float* b2  = (const float*)d_in[4];
    const float* w3  = (const float*)d_in[5];
    const float* b3  = (const float*)d_in[6];
    const float* t   = (const float*)d_in[7];
    const float* th  = (const float*)d_in[8];
    const float* gw1 = (const float*)d_in[9];
    const float* gb1 = (const float*)d_in[10];
    const float* gw2 = (const float*)d_in[11];
    const float* gb2 = (const float*)d_in[12];
    const float* lw1 = (const float*)d_in[13];
    const float* lb1 = (const float*)d_in[14];
    const float* lw2 = (const float*)d_in[15];
    const float* lb2 = (const float*)d_in[16];

    char* ws = (char*)d_ws;
    float* wt1 = (float*)(ws + 0);         // [256][512]
    float* wt2 = (float*)(ws + 524288);    // [256][256]
    float* wt3 = (float*)(ws + 786432);    // [32][256]
    float* H1  = (float*)(ws + 819200);    // [8192][256]  (aliased by P later)
    float* P   = (float*)(ws + 819200);    // [8][8192][16] partials (4MB, H1 dead by then)
    float* H2  = (float*)(ws + 9207808);   // [8192][256]
    float* H   = (float*)(ws + 17596416);  // [8192][32]
    u16*   hhi = (u16*)(ws + 18644992);    // [8192][32] bf16 hi
    u16*   hlo = (u16*)(ws + 19169280);    // [8192][32] bf16 lo
    float* sqv = (float*)(ws + 19693568);  // [8192]
    u16*   B1t = (u16*)(ws + 19726336);    // [16][8192] bf16
    u16*   B2t = (u16*)(ws + 19988480);    // [16][8192] bf16 (rows 8..15 zero)

    k_tr<<<(512 * 256 + 255) / 256, 256, 0, stream>>>(w1, wt1, 512, 256);
    k_tr<<<(256 * 256 + 255) / 256, 256, 0, stream>>>(w2, wt2, 256, 256);
    k_tr<<<(256 * 32 + 255) / 256, 256, 0, stream>>>(w3, wt3, 256, 32);

    k_gemm<512, 64, true ><<<dim3(128, 4), 256, 0, stream>>>(x,  wt1, b1, H1, 256);
    k_gemm<256, 64, true ><<<dim3(128, 4), 256, 0, stream>>>(H1, wt2, b2, H2, 256);
    k_gemm<256, 32, false><<<dim3(128, 1), 256, 0, stream>>>(H2, wt3, b3, H, 32);

    k_post<<<32, 256, 0, stream>>>(H, gw1, hhi, hlo, sqv, B1t);

    k_agg<<<dim3(128, 8), 256, 0, stream>>>(hhi, hlo, sqv, B1t, P, t, th);
    k_reduce1<<<32, 256, 0, stream>>>(P, gw2, gb1, B2t);
    k_agg<<<dim3(128, 8), 256, 0, stream>>>(hhi, hlo, sqv, B2t, P, t, th);
    k_final<<<32, 256, 0, stream>>>(P, gb2, lw1, lb1, lw2, lb2, (float*)d_out);
}